// Round 1
// baseline (884.487 us; speedup 1.0000x reference)
//
#include <hip/hip_runtime.h>
#include <cstdint>
#include <cstddef>

#define DIM 128
#define HEADS 4

// ---------------------------------------------------------------------------
// Kernel 1: fused QKV GEMM.  Out[n][j] = sum_k emb[n][k] * W[k][j]
// M = num_nodes, N = 128, K = 128.  blockIdx.y in {0,1,2} selects qW/kW/vW.
// BM=128 rows per block, BK=32, 256 threads, 8x8 accumulator per thread.
// ---------------------------------------------------------------------------
#define BM 128
#define BK 32

__global__ __launch_bounds__(256)
void qkv_gemm(const float* __restrict__ emb,
              const float* __restrict__ qW, const float* __restrict__ kW,
              const float* __restrict__ vW,
              float* __restrict__ Qo, float* __restrict__ Ko, float* __restrict__ Vo,
              int N)
{
    __shared__ float Ast[BK][BM + 4];   // A tile transposed: Ast[k][row], stride 132 (528B = 16B-aligned)
    __shared__ float Ws [BK][DIM + 4];  // W tile: Ws[k][col], stride 132

    const int wsel = blockIdx.y;
    const float* __restrict__ W   = (wsel == 0) ? qW : (wsel == 1) ? kW : vW;
    float* __restrict__       Out = (wsel == 0) ? Qo : (wsel == 1) ? Ko : Vo;

    const int tid = threadIdx.x;
    const int tx = tid & 15;       // 16 col-groups
    const int ty = tid >> 4;       // 16 row-groups
    const int m0 = blockIdx.x * BM;

    float acc[8][8];
#pragma unroll
    for (int i = 0; i < 8; i++)
#pragma unroll
        for (int j = 0; j < 8; j++) acc[i][j] = 0.f;

    for (int k0 = 0; k0 < DIM; k0 += BK) {
        // ---- load A tile (128 rows x 32 k), transpose into LDS ----
#pragma unroll
        for (int p = 0; p < 4; p++) {
            int row = (tid >> 3) + p * 32;        // 0..127
            int k4  = (tid & 7) * 4;              // 0..28
            float4 a = make_float4(0.f, 0.f, 0.f, 0.f);
            int gr = m0 + row;
            if (gr < N) a = *(const float4*)(emb + (size_t)gr * DIM + k0 + k4);
            Ast[k4 + 0][row] = a.x;
            Ast[k4 + 1][row] = a.y;
            Ast[k4 + 2][row] = a.z;
            Ast[k4 + 3][row] = a.w;
        }
        // ---- load W tile (32 k x 128 cols) ----
#pragma unroll
        for (int p = 0; p < 4; p++) {
            int kr = (tid >> 5) + p * 8;          // 0..31
            int c4 = (tid & 31) * 4;              // 0..124
            *(float4*)&Ws[kr][c4] = *(const float4*)(W + (size_t)(k0 + kr) * DIM + c4);
        }
        __syncthreads();

#pragma unroll 8
        for (int kk = 0; kk < BK; kk++) {
            float4 a0 = *(const float4*)&Ast[kk][ty * 8];
            float4 a1 = *(const float4*)&Ast[kk][ty * 8 + 4];
            float4 w0 = *(const float4*)&Ws[kk][tx * 4];
            float4 w1 = *(const float4*)&Ws[kk][tx * 4 + 64];
            float av[8] = {a0.x, a0.y, a0.z, a0.w, a1.x, a1.y, a1.z, a1.w};
            float wv[8] = {w0.x, w0.y, w0.z, w0.w, w1.x, w1.y, w1.z, w1.w};
#pragma unroll
            for (int i = 0; i < 8; i++)
#pragma unroll
                for (int j = 0; j < 8; j++)
                    acc[i][j] += av[i] * wv[j];
        }
        __syncthreads();
    }

    // ---- store: rows ty*8..+8, cols tx*4..+4 and tx*4+64..+4 ----
#pragma unroll
    for (int i = 0; i < 8; i++) {
        int row = m0 + ty * 8 + i;
        if (row < N) {
            float4 r0 = make_float4(acc[i][0], acc[i][1], acc[i][2], acc[i][3]);
            float4 r1 = make_float4(acc[i][4], acc[i][5], acc[i][6], acc[i][7]);
            *(float4*)(Out + (size_t)row * DIM + tx * 4)      = r0;
            *(float4*)(Out + (size_t)row * DIM + tx * 4 + 64) = r1;
        }
    }
}

// ---------------------------------------------------------------------------
// Kernel 2: per-edge attention logits + exp + segment-sum denominator.
// 4 lanes per edge (one per head), float4 gathers.
// ---------------------------------------------------------------------------
__global__ __launch_bounds__(256)
void edge_logits(const float* __restrict__ Q, const float* __restrict__ K,
                 const int* __restrict__ rows, const int* __restrict__ cols,
                 float* __restrict__ expAtt, float* __restrict__ attNorm, int E)
{
    int t = blockIdx.x * 256 + threadIdx.x;
    int e = t >> 2;
    int h = t & 3;
    if (e >= E) return;
    int r = rows[e];
    int c = cols[e];
    const float4* qp = (const float4*)(Q + (size_t)r * DIM + h * 32);
    const float4* kp = (const float4*)(K + (size_t)c * DIM + h * 32);
    float dot = 0.f;
#pragma unroll
    for (int i = 0; i < 8; i++) {
        float4 a = qp[i];
        float4 b = kp[i];
        dot += a.x * b.x + a.y * b.y + a.z * b.z + a.w * b.w;
    }
    dot = fminf(fmaxf(dot, -10.f), 10.f);
    float ex = expf(dot);
    expAtt[(size_t)e * HEADS + h] = ex;
    atomicAdd(&attNorm[(size_t)r * HEADS + h], ex);
}

// ---------------------------------------------------------------------------
// Kernel 3: normalize att, write att output, scatter att*V into out[rows].
// 32 lanes per edge, 4 dims per lane (float4), f32 global atomics.
// ---------------------------------------------------------------------------
__global__ __launch_bounds__(256)
void edge_scatter(const float* __restrict__ V,
                  const float* __restrict__ expAtt, const float* __restrict__ attNorm,
                  const int* __restrict__ rows, const int* __restrict__ cols,
                  float* __restrict__ out, float* __restrict__ attOut, int E)
{
    int t = blockIdx.x * 256 + threadIdx.x;
    int e = t >> 5;
    int lane = t & 31;
    if (e >= E) return;
    int r = rows[e];
    int c = cols[e];
    int h = lane >> 3;                      // dims lane*4..+4 -> head lane/8
    float ex   = expAtt[(size_t)e * HEADS + h];
    float norm = attNorm[(size_t)r * HEADS + h];
    float a = ex / (norm + 1e-8f);
    if ((lane & 7) == 0) attOut[(size_t)e * HEADS + h] = a;
    float4 v = *(const float4*)(V + (size_t)c * DIM + lane * 4);
    float* o = out + (size_t)r * DIM + lane * 4;
    atomicAdd(o + 0, a * v.x);
    atomicAdd(o + 1, a * v.y);
    atomicAdd(o + 2, a * v.z);
    atomicAdd(o + 3, a * v.w);
}

// ---------------------------------------------------------------------------
// kernel_launch
// inputs: embeds[N*128] f32, qW[128*128], kW, vW, rows[E] i32, cols[E] i32, num_nodes
// output: out[N*128] f32 ++ att[E*4] f32
// workspace: Q,K,V (3*N*128 f32) + expAtt (E*4) + attNorm (N*4)  ~162 MB
// ---------------------------------------------------------------------------
extern "C" void kernel_launch(void* const* d_in, const int* in_sizes, int n_in,
                              void* d_out, int out_size, void* d_ws, size_t ws_size,
                              hipStream_t stream)
{
    const float* emb = (const float*)d_in[0];
    const float* qW  = (const float*)d_in[1];
    const float* kW  = (const float*)d_in[2];
    const float* vW  = (const float*)d_in[3];
    const int*   rows = (const int*)d_in[4];
    const int*   cols = (const int*)d_in[5];

    const int N = in_sizes[0] / DIM;
    const int E = in_sizes[4];

    float* dout   = (float*)d_out;
    float* outMat = dout;                       // [N,128]
    float* attOut = dout + (size_t)N * DIM;     // [E,4]

    float* ws      = (float*)d_ws;
    float* Q       = ws;
    float* K       = ws + (size_t)N * DIM;
    float* V       = ws + 2 * (size_t)N * DIM;
    float* expAtt  = ws + 3 * (size_t)N * DIM;  // [E,4]
    float* attNorm = expAtt + (size_t)E * HEADS; // [N,4]

    // zero the accumulation targets (atomics accumulate; harness doesn't re-zero)
    hipMemsetAsync(outMat, 0, (size_t)N * DIM * sizeof(float), stream);
    hipMemsetAsync(attNorm, 0, (size_t)N * HEADS * sizeof(float), stream);

    dim3 ggrid((N + BM - 1) / BM, 3);
    qkv_gemm<<<ggrid, 256, 0, stream>>>(emb, qW, kW, vW, Q, K, V, N);

    int lblocks = (E * 4 + 255) / 256;
    edge_logits<<<lblocks, 256, 0, stream>>>(Q, K, rows, cols, expAtt, attNorm, E);

    int sblocks = (E * 32 + 255) / 256;
    edge_scatter<<<sblocks, 256, 0, stream>>>(V, expAtt, attNorm, rows, cols,
                                              outMat, attOut, E);
}

// Round 2
// 335.989 us; speedup vs baseline: 2.6325x; 2.6325x over previous
//
#include <hip/hip_runtime.h>
#include <cstdint>
#include <cstddef>

#define DIM 128
#define HEADS 4

// ---------------------------------------------------------------------------
// Kernel 1: fused QKV GEMM.  Out[n][j] = sum_k emb[n][k] * W[k][j]
// M = num_nodes, N = 128, K = 128.  blockIdx.y in {0,1,2} selects qW/kW/vW.
// ---------------------------------------------------------------------------
#define BM 128
#define BK 32

__global__ __launch_bounds__(256)
void qkv_gemm(const float* __restrict__ emb,
              const float* __restrict__ qW, const float* __restrict__ kW,
              const float* __restrict__ vW,
              float* __restrict__ Qo, float* __restrict__ Ko, float* __restrict__ Vo,
              int N)
{
    __shared__ float Ast[BK][BM + 4];
    __shared__ float Ws [BK][DIM + 4];

    const int wsel = blockIdx.y;
    const float* __restrict__ W   = (wsel == 0) ? qW : (wsel == 1) ? kW : vW;
    float* __restrict__       Out = (wsel == 0) ? Qo : (wsel == 1) ? Ko : Vo;

    const int tid = threadIdx.x;
    const int tx = tid & 15;
    const int ty = tid >> 4;
    const int m0 = blockIdx.x * BM;

    float acc[8][8];
#pragma unroll
    for (int i = 0; i < 8; i++)
#pragma unroll
        for (int j = 0; j < 8; j++) acc[i][j] = 0.f;

    for (int k0 = 0; k0 < DIM; k0 += BK) {
#pragma unroll
        for (int p = 0; p < 4; p++) {
            int row = (tid >> 3) + p * 32;
            int k4  = (tid & 7) * 4;
            float4 a = make_float4(0.f, 0.f, 0.f, 0.f);
            int gr = m0 + row;
            if (gr < N) a = *(const float4*)(emb + (size_t)gr * DIM + k0 + k4);
            Ast[k4 + 0][row] = a.x;
            Ast[k4 + 1][row] = a.y;
            Ast[k4 + 2][row] = a.z;
            Ast[k4 + 3][row] = a.w;
        }
#pragma unroll
        for (int p = 0; p < 4; p++) {
            int kr = (tid >> 5) + p * 8;
            int c4 = (tid & 31) * 4;
            *(float4*)&Ws[kr][c4] = *(const float4*)(W + (size_t)(k0 + kr) * DIM + c4);
        }
        __syncthreads();

#pragma unroll 8
        for (int kk = 0; kk < BK; kk++) {
            float4 a0 = *(const float4*)&Ast[kk][ty * 8];
            float4 a1 = *(const float4*)&Ast[kk][ty * 8 + 4];
            float4 w0 = *(const float4*)&Ws[kk][tx * 4];
            float4 w1 = *(const float4*)&Ws[kk][tx * 4 + 64];
            float av[8] = {a0.x, a0.y, a0.z, a0.w, a1.x, a1.y, a1.z, a1.w};
            float wv[8] = {w0.x, w0.y, w0.z, w0.w, w1.x, w1.y, w1.z, w1.w};
#pragma unroll
            for (int i = 0; i < 8; i++)
#pragma unroll
                for (int j = 0; j < 8; j++)
                    acc[i][j] += av[i] * wv[j];
        }
        __syncthreads();
    }

#pragma unroll
    for (int i = 0; i < 8; i++) {
        int row = m0 + ty * 8 + i;
        if (row < N) {
            float4 r0 = make_float4(acc[i][0], acc[i][1], acc[i][2], acc[i][3]);
            float4 r1 = make_float4(acc[i][4], acc[i][5], acc[i][6], acc[i][7]);
            *(float4*)(Out + (size_t)row * DIM + tx * 4)      = r0;
            *(float4*)(Out + (size_t)row * DIM + tx * 4 + 64) = r1;
        }
    }
}

// ---------------------------------------------------------------------------
// Kernel 2: per-edge logits -> exp, written to attBuf (= att slot of d_out).
// No atomics: denominator computed later per-node in csr_gather.
// ---------------------------------------------------------------------------
__global__ __launch_bounds__(256)
void edge_logits(const float* __restrict__ Q, const float* __restrict__ K,
                 const int* __restrict__ rows, const int* __restrict__ cols,
                 float* __restrict__ attBuf, int E)
{
    int t = blockIdx.x * 256 + threadIdx.x;
    int e = t >> 2;
    int h = t & 3;
    if (e >= E) return;
    int r = rows[e];
    int c = cols[e];
    const float4* qp = (const float4*)(Q + (size_t)r * DIM + h * 32);
    const float4* kp = (const float4*)(K + (size_t)c * DIM + h * 32);
    float dot = 0.f;
#pragma unroll
    for (int i = 0; i < 8; i++) {
        float4 a = qp[i];
        float4 b = kp[i];
        dot += a.x * b.x + a.y * b.y + a.z * b.z + a.w * b.w;
    }
    dot = fminf(fmaxf(dot, -10.f), 10.f);
    attBuf[(size_t)e * HEADS + h] = expf(dot);
}

// ---------------------------------------------------------------------------
// CSR build: degree count -> exclusive scan -> permutation fill.
// ---------------------------------------------------------------------------
__global__ __launch_bounds__(256)
void count_degree(const int* __restrict__ rows, int* __restrict__ degree, int E)
{
    int e = blockIdx.x * 256 + threadIdx.x;
    if (e < E) atomicAdd(&degree[rows[e]], 1);
}

// scanA: per-block (1024 elems) exclusive scan of degree into rowPtr + block sums
__global__ __launch_bounds__(256)
void scanA(const int* __restrict__ degree, int* __restrict__ rowPtr,
           int* __restrict__ blockSums, int N)
{
    __shared__ int s[256];
    const int tid = threadIdx.x;
    const int base = blockIdx.x * 1024 + tid * 4;
    int d[4];
    int tsum = 0;
#pragma unroll
    for (int i = 0; i < 4; i++) {
        d[i] = (base + i < N) ? degree[base + i] : 0;
        tsum += d[i];
    }
    s[tid] = tsum;
    __syncthreads();
    for (int off = 1; off < 256; off <<= 1) {
        int v = (tid >= off) ? s[tid - off] : 0;
        __syncthreads();
        s[tid] += v;
        __syncthreads();
    }
    if (tid == 255) blockSums[blockIdx.x] = s[255];
    int running = s[tid] - tsum;   // exclusive base for this thread
#pragma unroll
    for (int i = 0; i < 4; i++) {
        if (base + i < N) rowPtr[base + i] = running;
        running += d[i];
    }
}

// scanB: single block, exclusive scan of blockSums (nb <= 128)
__global__ __launch_bounds__(256)
void scanB(int* __restrict__ blockSums, int nb)
{
    __shared__ int s[256];
    const int tid = threadIdx.x;
    int v = (tid < nb) ? blockSums[tid] : 0;
    s[tid] = v;
    __syncthreads();
    for (int off = 1; off < 256; off <<= 1) {
        int u = (tid >= off) ? s[tid - off] : 0;
        __syncthreads();
        s[tid] += u;
        __syncthreads();
    }
    if (tid < nb) blockSums[tid] = s[tid] - v;  // exclusive
}

// scanC: add block offsets, copy into cursor, set rowPtr[N] = E
__global__ __launch_bounds__(256)
void scanC(int* __restrict__ rowPtr, const int* __restrict__ blockSums,
           int* __restrict__ cursor, int N, int E)
{
    const int tid = threadIdx.x;
    const int base = blockIdx.x * 1024 + tid * 4;
    const int off = blockSums[blockIdx.x];
#pragma unroll
    for (int i = 0; i < 4; i++) {
        int idx = base + i;
        if (idx < N) {
            int v = rowPtr[idx] + off;
            rowPtr[idx] = v;
            cursor[idx] = v;
        }
    }
    if (blockIdx.x == 0 && tid == 0) rowPtr[N] = E;
}

__global__ __launch_bounds__(256)
void fill_perm(const int* __restrict__ rows, int* __restrict__ cursor,
               int* __restrict__ perm, int E)
{
    int e = blockIdx.x * 256 + threadIdx.x;
    if (e >= E) return;
    int pos = atomicAdd(&cursor[rows[e]], 1);
    perm[pos] = e;
}

// ---------------------------------------------------------------------------
// Kernel 4: per-node gather. 32 lanes per node, 4 dims per lane.
// Pass 1: local softmax denominator. Pass 2: normalize (overwrite attBuf
// in place with normalized att) and accumulate att * V[col] in registers.
// Single coalesced write of out[n].  NO atomics.
// ---------------------------------------------------------------------------
__global__ __launch_bounds__(256)
void csr_gather(const float* __restrict__ V, const int* __restrict__ rowPtr,
                const int* __restrict__ perm, const int* __restrict__ cols,
                float* __restrict__ attBuf,   // exp in, normalized out (d_out att slot)
                float* __restrict__ out, int N)
{
    int t = blockIdx.x * 256 + threadIdx.x;
    int node = t >> 5;
    int lane = t & 31;
    if (node >= N) return;
    const int start = rowPtr[node];
    const int end   = rowPtr[node + 1];
    const int h = lane >> 3;           // head for dims lane*4..lane*4+3

    float norm = 0.f;
    for (int p = start; p < end; p++) {
        int e = perm[p];
        norm += attBuf[(size_t)e * HEADS + h];
    }
    const float inv = 1.f / (norm + 1e-8f);

    float4 acc = make_float4(0.f, 0.f, 0.f, 0.f);
    for (int p = start; p < end; p++) {
        int e = perm[p];
        int c = cols[e];
        float a = attBuf[(size_t)e * HEADS + h] * inv;
        if ((lane & 7) == 0) attBuf[(size_t)e * HEADS + h] = a;
        float4 v = *(const float4*)(V + (size_t)c * DIM + lane * 4);
        acc.x += a * v.x;
        acc.y += a * v.y;
        acc.z += a * v.z;
        acc.w += a * v.w;
    }
    *(float4*)(out + (size_t)node * DIM + lane * 4) = acc;
}

// ---------------------------------------------------------------------------
// kernel_launch
// ws layout: Q,K,V (3*N*128 f32) | rowPtr(N+1) | blockSums(128) | cursor(N)
//            | perm(E) | degree(N)   (~156 MB)
// ---------------------------------------------------------------------------
extern "C" void kernel_launch(void* const* d_in, const int* in_sizes, int n_in,
                              void* d_out, int out_size, void* d_ws, size_t ws_size,
                              hipStream_t stream)
{
    const float* emb  = (const float*)d_in[0];
    const float* qW   = (const float*)d_in[1];
    const float* kW   = (const float*)d_in[2];
    const float* vW   = (const float*)d_in[3];
    const int*   rows = (const int*)d_in[4];
    const int*   cols = (const int*)d_in[5];

    const int N = in_sizes[0] / DIM;
    const int E = in_sizes[4];

    float* dout   = (float*)d_out;
    float* outMat = dout;                       // [N,128]
    float* attBuf = dout + (size_t)N * DIM;     // [E,4]  (exp staged, normalized in place)

    float* ws   = (float*)d_ws;
    float* Q    = ws;
    float* K    = ws + (size_t)N * DIM;
    float* V    = ws + 2 * (size_t)N * DIM;
    int* rowPtr    = (int*)(ws + 3 * (size_t)N * DIM);
    int* blockSums = rowPtr + (N + 1);
    int* cursor    = blockSums + 128;
    int* perm      = cursor + N;
    int* degree    = perm + E;

    hipMemsetAsync(degree, 0, (size_t)N * sizeof(int), stream);

    dim3 ggrid((N + BM - 1) / BM, 3);
    qkv_gemm<<<ggrid, 256, 0, stream>>>(emb, qW, kW, vW, Q, K, V, N);

    int lblocks = (E * 4 + 255) / 256;
    edge_logits<<<lblocks, 256, 0, stream>>>(Q, K, rows, cols, attBuf, E);

    int eblocks = (E + 255) / 256;
    count_degree<<<eblocks, 256, 0, stream>>>(rows, degree, E);

    int nb = (N + 1023) / 1024;
    scanA<<<nb, 256, 0, stream>>>(degree, rowPtr, blockSums, N);
    scanB<<<1, 256, 0, stream>>>(blockSums, nb);
    scanC<<<nb, 256, 0, stream>>>(rowPtr, blockSums, cursor, N, E);

    fill_perm<<<eblocks, 256, 0, stream>>>(rows, cursor, perm, E);

    int gblocks = (N * 32 + 255) / 256;
    csr_gather<<<gblocks, 256, 0, stream>>>(V, rowPtr, perm, cols, attBuf, outMat, N);
}

// Round 3
// 200.441 us; speedup vs baseline: 4.4127x; 1.6762x over previous
//
#include <hip/hip_runtime.h>
#include <cstdint>
#include <cstddef>

#define DIM 128
#define HEADS 4

typedef __attribute__((ext_vector_type(8))) short bf16x8;
typedef __attribute__((ext_vector_type(4))) float f32x4;

__device__ __forceinline__ ushort f2bf(float x) {
    union { float f; uint32_t u; } v; v.f = x;
    uint32_t r = v.u + 0x7FFFu + ((v.u >> 16) & 1u);   // RNE
    return (ushort)(r >> 16);
}
__device__ __forceinline__ float bf2f(ushort h) {
    union { uint32_t u; float f; } v; v.u = ((uint32_t)h) << 16; return v.f;
}

// ---------------------------------------------------------------------------
// wtrans: W[k][col] f32 -> Wt[w][col][k] bf16 hi/lo (transposed for B-frags)
// ---------------------------------------------------------------------------
__global__ __launch_bounds__(256)
void wtrans(const float* __restrict__ qW, const float* __restrict__ kW,
            const float* __restrict__ vW,
            ushort* __restrict__ WtHi, ushort* __restrict__ WtLo)
{
    int t = blockIdx.x * 256 + threadIdx.x;      // 3*128*128 = 49152
    int w = t >> 14;
    int rem = t & 16383;
    int col = rem >> 7;
    int k = rem & 127;
    const float* W = (w == 0) ? qW : (w == 1) ? kW : vW;
    float x = W[k * DIM + col];
    ushort hi = f2bf(x);
    ushort lo = f2bf(x - bf2f(hi));
    WtHi[t] = hi;                                // [w][col][k]
    WtLo[t] = lo;
}

// ---------------------------------------------------------------------------
// qkv_mfma: Out = emb @ W via 3-term hi/lo bf16 MFMA (f32-quality).
// BM=128 rows/block, K processed in 2 chunks of 64. 256 thr = 4 waves,
// wave w computes rows [w*32, w*32+32) x all 128 cols.
// LDS tiles XOR-swizzled: byte ^= (row&7)<<4 (G4, bank-conflict-free b128).
// Outputs stored bf16.
// ---------------------------------------------------------------------------
__global__ __launch_bounds__(256)
void qkv_mfma(const float* __restrict__ emb,
              const ushort* __restrict__ WtHi, const ushort* __restrict__ WtLo,
              ushort* __restrict__ Qb, ushort* __restrict__ Kb,
              ushort* __restrict__ Vb, int N)
{
    __shared__ ushort Ahi[128 * 64], Alo[128 * 64];   // [row][k] 16KB each
    __shared__ ushort Bhi[128 * 64], Blo[128 * 64];   // [col][k] 16KB each

    const int wsel = blockIdx.y;
    const ushort* __restrict__ Wh = WtHi + wsel * DIM * DIM;
    const ushort* __restrict__ Wl = WtLo + wsel * DIM * DIM;
    ushort* __restrict__ Out = (wsel == 0) ? Qb : (wsel == 1) ? Kb : Vb;

    const int tid = threadIdx.x;
    const int wv = tid >> 6;
    const int ln = tid & 63;
    const int l15 = ln & 15;
    const int l4 = ln >> 4;
    const int m0 = blockIdx.x * 128;

    f32x4 acc[2][8] = {};

    for (int c = 0; c < 2; c++) {
        // ---- stage A: 128 rows x 64 k, f32 -> bf16 hi/lo ----
#pragma unroll
        for (int p = 0; p < 8; p++) {
            int idx = tid + p * 256;            // 0..2047
            int row = idx >> 4;                 // 0..127
            int k4 = (idx & 15) << 2;           // 0..60
            float4 a = make_float4(0.f, 0.f, 0.f, 0.f);
            if (m0 + row < N)
                a = *(const float4*)(emb + (size_t)(m0 + row) * DIM + c * 64 + k4);
            ushort4 h, l;
            h.x = f2bf(a.x); l.x = f2bf(a.x - bf2f(h.x));
            h.y = f2bf(a.y); l.y = f2bf(a.y - bf2f(h.y));
            h.z = f2bf(a.z); l.z = f2bf(a.z - bf2f(h.z));
            h.w = f2bf(a.w); l.w = f2bf(a.w - bf2f(h.w));
            int boff = row * 128 + ((k4 * 2) ^ ((row & 7) << 4));
            *(ushort4*)((char*)Ahi + boff) = h;
            *(ushort4*)((char*)Alo + boff) = l;
        }
        // ---- stage B: 128 cols x 64 k bf16 (already split) ----
#pragma unroll
        for (int p = 0; p < 4; p++) {
            int idx = tid + p * 256;            // 0..1023
            int col = idx >> 3;                 // 0..127
            int k8 = (idx & 7) << 3;            // 0..56
            int goff = col * DIM + c * 64 + k8;
            uint4 hv = *(const uint4*)(Wh + goff);
            uint4 lv = *(const uint4*)(Wl + goff);
            int boff = col * 128 + ((k8 * 2) ^ ((col & 7) << 4));
            *(uint4*)((char*)Bhi + boff) = hv;
            *(uint4*)((char*)Blo + boff) = lv;
        }
        __syncthreads();

        // ---- A fragments: row = base + (ln&15), k = (ln>>4)*8 + i ----
        bf16x8 ah[2][2], al[2][2];
#pragma unroll
        for (int fr = 0; fr < 2; fr++)
#pragma unroll
            for (int s = 0; s < 2; s++) {
                int row = wv * 32 + fr * 16 + l15;
                int kb2 = (s * 32 + l4 * 8) * 2;
                int boff = row * 128 + (kb2 ^ ((row & 7) << 4));
                ah[fr][s] = *(bf16x8*)((char*)Ahi + boff);
                al[fr][s] = *(bf16x8*)((char*)Alo + boff);
            }
#pragma unroll
        for (int n = 0; n < 8; n++) {
            int col = n * 16 + l15;
            int cb = col * 128;
            int sw = (col & 7) << 4;
            int kb2 = l4 * 16;
            bf16x8 bh0 = *(bf16x8*)((char*)Bhi + cb + (kb2 ^ sw));
            bf16x8 bh1 = *(bf16x8*)((char*)Bhi + cb + ((kb2 + 64) ^ sw));
            bf16x8 bl0 = *(bf16x8*)((char*)Blo + cb + (kb2 ^ sw));
            bf16x8 bl1 = *(bf16x8*)((char*)Blo + cb + ((kb2 + 64) ^ sw));
#pragma unroll
            for (int fr = 0; fr < 2; fr++) {
                acc[fr][n] = __builtin_amdgcn_mfma_f32_16x16x32_bf16(ah[fr][0], bh0, acc[fr][n], 0, 0, 0);
                acc[fr][n] = __builtin_amdgcn_mfma_f32_16x16x32_bf16(al[fr][0], bh0, acc[fr][n], 0, 0, 0);
                acc[fr][n] = __builtin_amdgcn_mfma_f32_16x16x32_bf16(ah[fr][0], bl0, acc[fr][n], 0, 0, 0);
                acc[fr][n] = __builtin_amdgcn_mfma_f32_16x16x32_bf16(ah[fr][1], bh1, acc[fr][n], 0, 0, 0);
                acc[fr][n] = __builtin_amdgcn_mfma_f32_16x16x32_bf16(al[fr][1], bh1, acc[fr][n], 0, 0, 0);
                acc[fr][n] = __builtin_amdgcn_mfma_f32_16x16x32_bf16(ah[fr][1], bl1, acc[fr][n], 0, 0, 0);
            }
        }
        __syncthreads();
    }

    // ---- epilogue: C/D layout col=lane&15, row=(lane>>4)*4+j (m89) ----
#pragma unroll
    for (int fr = 0; fr < 2; fr++) {
        int rbase = m0 + wv * 32 + fr * 16 + l4 * 4;
#pragma unroll
        for (int n = 0; n < 8; n++) {
            int col = n * 16 + l15;
#pragma unroll
            for (int j = 0; j < 4; j++) {
                int r = rbase + j;
                if (r < N) Out[(size_t)r * DIM + col] = f2bf(acc[fr][n][j]);
            }
        }
    }
}

// ---------------------------------------------------------------------------
// CSR build: degree count -> exclusive scan -> permutation fill (+ colsCSR).
// ---------------------------------------------------------------------------
__global__ __launch_bounds__(256)
void count_degree(const int* __restrict__ rows, int* __restrict__ degree, int E)
{
    int e = blockIdx.x * 256 + threadIdx.x;
    if (e < E) atomicAdd(&degree[rows[e]], 1);
}

__global__ __launch_bounds__(256)
void scanA(const int* __restrict__ degree, int* __restrict__ rowPtr,
           int* __restrict__ blockSums, int N)
{
    __shared__ int s[256];
    const int tid = threadIdx.x;
    const int base = blockIdx.x * 1024 + tid * 4;
    int d[4];
    int tsum = 0;
#pragma unroll
    for (int i = 0; i < 4; i++) {
        d[i] = (base + i < N) ? degree[base + i] : 0;
        tsum += d[i];
    }
    s[tid] = tsum;
    __syncthreads();
    for (int off = 1; off < 256; off <<= 1) {
        int v = (tid >= off) ? s[tid - off] : 0;
        __syncthreads();
        s[tid] += v;
        __syncthreads();
    }
    if (tid == 255) blockSums[blockIdx.x] = s[255];
    int running = s[tid] - tsum;
#pragma unroll
    for (int i = 0; i < 4; i++) {
        if (base + i < N) rowPtr[base + i] = running;
        running += d[i];
    }
}

__global__ __launch_bounds__(256)
void scanB(int* __restrict__ blockSums, int nb)
{
    __shared__ int s[256];
    const int tid = threadIdx.x;
    int v = (tid < nb) ? blockSums[tid] : 0;
    s[tid] = v;
    __syncthreads();
    for (int off = 1; off < 256; off <<= 1) {
        int u = (tid >= off) ? s[tid - off] : 0;
        __syncthreads();
        s[tid] += u;
        __syncthreads();
    }
    if (tid < nb) blockSums[tid] = s[tid] - v;
}

__global__ __launch_bounds__(256)
void scanC(int* __restrict__ rowPtr, const int* __restrict__ blockSums,
           int* __restrict__ cursor, int N, int E)
{
    const int tid = threadIdx.x;
    const int base = blockIdx.x * 1024 + tid * 4;
    const int off = blockSums[blockIdx.x];
#pragma unroll
    for (int i = 0; i < 4; i++) {
        int idx = base + i;
        if (idx < N) {
            int v = rowPtr[idx] + off;
            rowPtr[idx] = v;
            cursor[idx] = v;
        }
    }
    if (blockIdx.x == 0 && tid == 0) rowPtr[N] = E;
}

__global__ __launch_bounds__(256)
void fill_perm(const int* __restrict__ rows, const int* __restrict__ cols,
               int* __restrict__ cursor, int* __restrict__ perm,
               int* __restrict__ colsCSR, int E)
{
    int e = blockIdx.x * 256 + threadIdx.x;
    if (e >= E) return;
    int pos = atomicAdd(&cursor[rows[e]], 1);
    perm[pos] = e;
    colsCSR[pos] = cols[e];
}

// ---------------------------------------------------------------------------
// csr_fused: per node (32 lanes), single pass over its edges:
// logits (8-lane shfl reduce per head) -> exp -> norm + unnormalized ex*V acc.
// Writes out = acc/norm (f32), ex to attBuf (normalized later), invNorm.
// ---------------------------------------------------------------------------
__global__ __launch_bounds__(256)
void csr_fused(const ushort* __restrict__ Qb, const ushort* __restrict__ Kb,
               const ushort* __restrict__ Vb,
               const int* __restrict__ rowPtr, const int* __restrict__ perm,
               const int* __restrict__ colsCSR,
               float* __restrict__ attBuf, float* __restrict__ invNorm,
               float* __restrict__ out, int N)
{
    int t = blockIdx.x * 256 + threadIdx.x;
    int node = t >> 5;
    int lane = t & 31;
    if (node >= N) return;

    const int start = rowPtr[node];
    const int end   = rowPtr[node + 1];
    const int h = lane >> 3;

    ushort4 qu = *(const ushort4*)(Qb + (size_t)node * DIM + lane * 4);
    float4 q = make_float4(bf2f(qu.x), bf2f(qu.y), bf2f(qu.z), bf2f(qu.w));

    float norm = 0.f;
    float4 acc = make_float4(0.f, 0.f, 0.f, 0.f);
    for (int p = start; p < end; p++) {
        int c = colsCSR[p];
        int e = perm[p];
        ushort4 ku = *(const ushort4*)(Kb + (size_t)c * DIM + lane * 4);
        ushort4 vu = *(const ushort4*)(Vb + (size_t)c * DIM + lane * 4);
        float d = bf2f(ku.x) * q.x + bf2f(ku.y) * q.y
                + bf2f(ku.z) * q.z + bf2f(ku.w) * q.w;
        d += __shfl_xor(d, 1, 64);
        d += __shfl_xor(d, 2, 64);
        d += __shfl_xor(d, 4, 64);
        d = fminf(fmaxf(d, -10.f), 10.f);
        float ex = __expf(d);
        if ((lane & 7) == 0) attBuf[(size_t)e * HEADS + h] = ex;
        norm += ex;
        acc.x += ex * bf2f(vu.x);
        acc.y += ex * bf2f(vu.y);
        acc.z += ex * bf2f(vu.z);
        acc.w += ex * bf2f(vu.w);
    }
    float inv = 1.f / (norm + 1e-8f);
    if ((lane & 7) == 0) invNorm[(size_t)node * HEADS + h] = inv;
    acc.x *= inv; acc.y *= inv; acc.z *= inv; acc.w *= inv;
    *(float4*)(out + (size_t)node * DIM + lane * 4) = acc;
}

// ---------------------------------------------------------------------------
// att_scale: attBuf[e][h] *= invNorm[rows[e]][h]   (finishes softmax)
// ---------------------------------------------------------------------------
__global__ __launch_bounds__(256)
void att_scale(float* __restrict__ attBuf, const float* __restrict__ invNorm,
               const int* __restrict__ rows, int E4)
{
    int t = blockIdx.x * 256 + threadIdx.x;
    if (t >= E4) return;
    int e = t >> 2;
    attBuf[t] *= invNorm[(size_t)rows[e] * 4 + (t & 3)];
}

// ---------------------------------------------------------------------------
// kernel_launch
// ws: Qb,Kb,Vb bf16 [N*128]*3 | WtHi,WtLo bf16 [3*128*128]*2 | invNorm f32[N*4]
//     | rowPtr[N+1] | blockSums[128] | cursor[N] | perm[E] | colsCSR[E]
//     | degree[N]          (~84 MB)
// ---------------------------------------------------------------------------
extern "C" void kernel_launch(void* const* d_in, const int* in_sizes, int n_in,
                              void* d_out, int out_size, void* d_ws, size_t ws_size,
                              hipStream_t stream)
{
    const float* emb  = (const float*)d_in[0];
    const float* qW   = (const float*)d_in[1];
    const float* kW   = (const float*)d_in[2];
    const float* vW   = (const float*)d_in[3];
    const int*   rows = (const int*)d_in[4];
    const int*   cols = (const int*)d_in[5];

    const int N = in_sizes[0] / DIM;
    const int E = in_sizes[4];

    float* dout   = (float*)d_out;
    float* outMat = dout;                        // [N,128]
    float* attBuf = dout + (size_t)N * DIM;      // [E,4]

    ushort* Qb   = (ushort*)d_ws;
    ushort* Kb   = Qb + (size_t)N * DIM;
    ushort* Vb   = Kb + (size_t)N * DIM;
    ushort* WtHi = Vb + (size_t)N * DIM;
    ushort* WtLo = WtHi + 3 * DIM * DIM;
    float* invNorm = (float*)(WtLo + 3 * DIM * DIM);
    int* rowPtr    = (int*)(invNorm + (size_t)N * HEADS);
    int* blockSums = rowPtr + (N + 1);
    int* cursor    = blockSums + 128;
    int* perm      = cursor + N;
    int* colsCSR   = perm + E;
    int* degree    = colsCSR + E;

    hipMemsetAsync(degree, 0, (size_t)N * sizeof(int), stream);

    wtrans<<<3 * DIM * DIM / 256, 256, 0, stream>>>(qW, kW, vW, WtHi, WtLo);

    dim3 ggrid((N + 127) / 128, 3);
    qkv_mfma<<<ggrid, 256, 0, stream>>>(emb, WtHi, WtLo, Qb, Kb, Vb, N);

    int eblocks = (E + 255) / 256;
    count_degree<<<eblocks, 256, 0, stream>>>(rows, degree, E);

    int nb = (N + 1023) / 1024;
    scanA<<<nb, 256, 0, stream>>>(degree, rowPtr, blockSums, N);
    scanB<<<1, 256, 0, stream>>>(blockSums, nb);
    scanC<<<nb, 256, 0, stream>>>(rowPtr, blockSums, cursor, N, E);

    fill_perm<<<eblocks, 256, 0, stream>>>(rows, cols, cursor, perm, colsCSR, E);

    int gblocks = (N * 32 + 255) / 256;
    csr_fused<<<gblocks, 256, 0, stream>>>(Qb, Kb, Vb, rowPtr, perm, colsCSR,
                                           attBuf, invNorm, outMat, N);

    int sblocks = (E * HEADS + 255) / 256;
    att_scale<<<sblocks, 256, 0, stream>>>(attBuf, invNorm, rows, E * HEADS);
}